// Round 7
// baseline (1863.936 us; speedup 1.0000x reference)
//
#include <hip/hip_runtime.h>
#include <hip/hip_bf16.h>
#include <math.h>

#define N_NODES 65536
#define HW      65536
#define NE      524288
#define NC      (N_NODES * 64)
#define CCAP    1280

typedef __bf16 bf16x8 __attribute__((ext_vector_type(8)));
typedef float  f32x4  __attribute__((ext_vector_type(4)));
typedef int    i32x4  __attribute__((ext_vector_type(4)));
typedef unsigned int uint2v __attribute__((ext_vector_type(2)));

static __device__ __forceinline__ f32x4 mfma16(bf16x8 a, bf16x8 b, f32x4 c) {
    return __builtin_amdgcn_mfma_f32_16x16x32_bf16(a, b, c, 0, 0, 0);
}

static __device__ __forceinline__ unsigned short f2bs(float f) {
    return __builtin_bit_cast(unsigned short, __float2bfloat16(f));
}

static __device__ __forceinline__ void unpack4(uint2v xw, f32x4& xj) {
    xj[0] = __builtin_bit_cast(float, xw[0] << 16);
    xj[1] = __builtin_bit_cast(float, xw[0] & 0xffff0000u);
    xj[2] = __builtin_bit_cast(float, xw[1] << 16);
    xj[3] = __builtin_bit_cast(float, xw[1] & 0xffff0000u);
}

// ---------------- CSR build ----------------
__global__ void k_hist(const int* __restrict__ dstA, int* __restrict__ cnt) {
    int e = blockIdx.x * 256 + threadIdx.x;
    if (e < NE) atomicAdd(&cnt[dstA[e]], 1);
}

__global__ void k_scan(const int* __restrict__ cnt, int* __restrict__ off) {
    __shared__ int sums[1024];
    int t = threadIdx.x;
    int base = t * 64;
    int s = 0;
    for (int i = 0; i < 64; ++i) s += cnt[base + i];
    sums[t] = s;
    __syncthreads();
    for (int d = 1; d < 1024; d <<= 1) {
        int v = (t >= d) ? sums[t - d] : 0;
        __syncthreads();
        sums[t] += v;
        __syncthreads();
    }
    int run = sums[t] - s;  // exclusive prefix
    for (int i = 0; i < 64; ++i) { off[base + i] = run; run += cnt[base + i]; }
    if (t == 1023) off[N_NODES] = run;
}

__global__ void k_fill(const int* __restrict__ srcA, const int* __restrict__ dstA,
                       int* __restrict__ cur, int* __restrict__ csr) {
    int e = blockIdx.x * 256 + threadIdx.x;
    if (e < NE) {
        int p = atomicAdd(&cur[dstA[e]], 1);
        csr[p] = srcA[e];
    }
}

// ---------------- degree sort: perm + permuted CSR ----------------
__global__ void k_dhist(const int* __restrict__ cnt, int* __restrict__ dh) {
    int n = blockIdx.x * 256 + threadIdx.x;
    if (n < N_NODES) atomicAdd(&dh[min(cnt[n], 63)], 1);
}

__global__ void k_dscan(const int* __restrict__ dh, int* __restrict__ dbase) {
    if (threadIdx.x == 0) {
        int r = 0;
        for (int i = 0; i < 64; ++i) { dbase[i] = r; r += dh[i]; }
    }
}

__global__ void k_dscatter(const int* __restrict__ cnt, int* __restrict__ dcur,
                           int* __restrict__ perm) {
    int n = blockIdx.x * 256 + threadIdx.x;
    if (n < N_NODES) {
        int b = min(cnt[n], 63);
        int r = atomicAdd(&dcur[b], 1);
        perm[r] = n;
    }
}

__global__ void k_permdeg(const int* __restrict__ perm, const int* __restrict__ cnt,
                          int* __restrict__ cnt2) {
    int i = blockIdx.x * 256 + threadIdx.x;
    if (i < N_NODES) cnt2[i] = cnt[perm[i]];
}

__global__ void k_csr2(const int* __restrict__ perm, const int* __restrict__ cnt,
                       const int* __restrict__ off, const int* __restrict__ off2,
                       const int* __restrict__ csr, int* __restrict__ csr2) {
    int i = blockIdx.x * 256 + threadIdx.x;
    if (i >= N_NODES) return;
    int n = perm[i];
    int s0 = off[n], d = cnt[n], t0 = off2[i];
    for (int j = 0; j < d; ++j) csr2[t0 + j] = csr[s0 + j];
}

// ---------------- weight packing (MFMA fragment order) ----------------
// conv: rb_w [16][co][ci][3][3] -> [cv][tap][nt][kk][lane][8] bf16
__global__ void k_cvpack(const float* __restrict__ w, __hip_bfloat16* __restrict__ d) {
    int idx = blockIdx.x * 256 + threadIdx.x;
    if (idx >= 589824) return;
    int j = idx & 7, lane = (idx >> 3) & 63, r = idx >> 9;
    int kk = r & 1; r >>= 1;
    int nt = r & 3; r >>= 2;
    int tap = r % 9, cv = r / 9;
    int co = nt * 16 + (lane & 15);
    int ci = kk * 32 + (lane >> 4) * 8 + j;
    d[idx] = __float2bfloat16(w[((cv * 64 + co) * 64 + ci) * 9 + tap]);
}

// gat mm: gWl/gWr [27][ci][co] -> [lay][side][nt][kk][lane][8] bf16
__global__ void k_mmpack(const float* __restrict__ Wl, const float* __restrict__ Wr,
                         __hip_bfloat16* __restrict__ d) {
    int idx = blockIdx.x * 256 + threadIdx.x;
    if (idx >= 221184) return;
    int j = idx & 7, lane = (idx >> 3) & 63, r = idx >> 9;
    int kk = r & 1; r >>= 1;
    int nt = r & 3; r >>= 2;
    int side = r & 1, lay = r >> 1;
    int co = nt * 16 + (lane & 15);
    int ci = kk * 32 + (lane >> 4) * 8 + j;
    const float* W = side ? Wr : Wl;
    d[idx] = __float2bfloat16(W[lay * 4096 + ci * 64 + co]);
}

// cc_w [3][o=64][k=192] -> [st][br][nt][kk][lane][8] bf16
__global__ void k_ccpack(const float* __restrict__ w, __hip_bfloat16* __restrict__ d) {
    int idx = blockIdx.x * 256 + threadIdx.x;
    if (idx >= 36864) return;
    int j = idx & 7;
    int u = idx >> 3;
    int lane = u & 63;
    int f = (u >> 6) & 7;
    int sb = u >> 9;
    int kk = f & 1, nt = f >> 1;
    int br = sb % 3, st = sb / 3;
    int k = br * 64 + kk * 32 + (lane >> 4) * 8 + j;
    int co = nt * 16 + (lane & 15);
    d[idx] = __float2bfloat16(w[st * 12288 + co * 192 + k]);
}

// ---------------- initial NCHW -> [N,64] fp32 + bf16 ----------------
__global__ void k_init(const float* __restrict__ img, float* __restrict__ xn,
                       __hip_bfloat16* __restrict__ xb) {
    __shared__ float tile[64][65];
    int nb = blockIdx.x * 64;
    for (int idx = threadIdx.x; idx < 4096; idx += 256) {
        int c = idx >> 6, n = idx & 63;
        tile[c][n] = img[c * HW + nb + n];
    }
    __syncthreads();
    for (int idx = threadIdx.x; idx < 4096; idx += 256) {
        int n = idx >> 6, c = idx & 63;
        float v = tile[c][n];
        xn[(nb + n) * 64 + c] = v;
        xb[(nb + n) * 64 + c] = __float2bfloat16(v);
    }
}

// ---------------- MFMA dual matmul: XLb = bf16(X@Wl), XRb = bf16(X@Wr) ----------------
__global__ __launch_bounds__(256) void k_mm(const __hip_bfloat16* __restrict__ Xb,
        const __hip_bfloat16* __restrict__ pw, __hip_bfloat16* __restrict__ XLb,
        __hip_bfloat16* __restrict__ XRb) {
    __shared__ i32x4 la[128 * 8];
    int t = threadIdx.x, lane = t & 63, wid = t >> 6;
    int n0 = blockIdx.x * 128;
    const i32x4* Xg = (const i32x4*)Xb + n0 * 8;
    for (int idx = t; idx < 1024; idx += 256) {
        int r = idx >> 3, c = idx & 7;
        la[r * 8 + (c ^ (r & 7))] = Xg[idx];
    }
    int side = wid & 1, rh = wid >> 1;
    const i32x4* wpt = (const i32x4*)pw + side * 512 + lane;
    f32x4 acc[4][4];
#pragma unroll
    for (int mi = 0; mi < 4; ++mi)
#pragma unroll
        for (int nt = 0; nt < 4; ++nt) acc[mi][nt] = (f32x4)0.0f;
    bf16x8 b[4][2];
#pragma unroll
    for (int nt = 0; nt < 4; ++nt)
#pragma unroll
        for (int kk = 0; kk < 2; ++kk)
            b[nt][kk] = __builtin_bit_cast(bf16x8, wpt[(nt * 2 + kk) * 64]);
    __syncthreads();
#pragma unroll
    for (int mi = 0; mi < 4; ++mi) {
        int row = rh * 64 + mi * 16 + (lane & 15);
#pragma unroll
        for (int kk = 0; kk < 2; ++kk) {
            bf16x8 a = __builtin_bit_cast(bf16x8,
                la[row * 8 + (((kk << 2) | (lane >> 4)) ^ (row & 7))]);
#pragma unroll
            for (int nt = 0; nt < 4; ++nt)
                acc[mi][nt] = mfma16(a, b[nt][kk], acc[mi][nt]);
        }
    }
    __hip_bfloat16* O = side ? XRb : XLb;
#pragma unroll
    for (int mi = 0; mi < 4; ++mi)
#pragma unroll
        for (int nt = 0; nt < 4; ++nt) {
            int co = nt * 16 + (lane & 15);
#pragma unroll
            for (int r = 0; r < 4; ++r) {
                int node = n0 + rh * 64 + mi * 16 + (lane >> 4) * 4 + r;
                O[node * 64 + co] = __float2bfloat16(acc[mi][nt][r]);
            }
        }
}

// ---------------- GAT edge phase (degree-sorted, 4 edges in flight) ----------------
// 16-lane group owns one node (4 ch/lane). Per-head softmax = quad reduce only.
// Nodes processed in degree-sorted perm order: equal degree within a wave ->
// zero loop divergence; csr2 contiguous per block -> LDS edge cache.
__global__ __launch_bounds__(256) void k_gat(const __hip_bfloat16* __restrict__ XLb,
        const __hip_bfloat16* __restrict__ XRb, const float* __restrict__ att64,
        const float* __restrict__ bias, const int* __restrict__ perm,
        const int* __restrict__ off2, const int* __restrict__ csr2,
        __hip_bfloat16* __restrict__ outb) {
    __shared__ int csr_c[CCAP];
    int tid = threadIdx.x;
    int lane = tid & 63;
    int g = (lane >> 4) & 3;
    int c4 = (lane & 15) << 2;
    int r0 = blockIdx.x * 32;
    int cbase = off2[r0];
    int ccnt = min(off2[r0 + 32] - cbase, CCAP);
    for (int idx = tid; idx < ccnt; idx += 256) csr_c[idx] = csr2[cbase + idx];
    __syncthreads();
    const float LOG2E = 1.44269504089f;
    f32x4 a4 = *(const f32x4*)(att64 + c4);
#pragma unroll
    for (int j = 0; j < 4; ++j) a4[j] *= LOG2E;
    f32x4 b4 = *(const f32x4*)(bias + c4);
    int rbase = r0 + ((tid >> 6) << 3) + g * 2;   // 2 consecutive ranks per group
#pragma unroll
    for (int nn = 0; nn < 2; ++nn) {
        int rk = rbase + nn;
        int n = perm[rk];
        int e0 = off2[rk], e1 = off2[rk + 1];
        uint2v xw = *(const uint2v*)(XRb + n * 64 + c4);
        f32x4 xi;
        unpack4(xw, xi);
        float s = 0.f;
        f32x4 acc = (f32x4)0.0f;
        for (int e = e0; e < e1; e += 4) {
            int src[4];
#pragma unroll
            for (int q = 0; q < 4; ++q) {
                int ee = (e + q) < e1 ? (e + q) : e0;
                int rr = ee - cbase;
                src[q] = (rr < ccnt) ? csr_c[rr] : csr2[ee];
            }
            uint2v w[4];
#pragma unroll
            for (int q = 0; q < 4; ++q)
                w[q] = *(const uint2v*)(XLb + src[q] * 64 + c4);   // 4 gathers in flight
            f32x4 xj[4];
            float ex[4];
#pragma unroll
            for (int q = 0; q < 4; ++q) {
                unpack4(w[q], xj[q]);
                float p = 0.f;
#pragma unroll
                for (int j = 0; j < 4; ++j) {
                    float v = xi[j] + xj[q][j];
                    v = fmaxf(v, 0.2f * v);          // leaky_relu(0.2)
                    p = fmaf(v, a4[j], p);
                }
                p += __shfl_xor(p, 1);
                p += __shfl_xor(p, 2);               // per-head logit (quad reduce)
                float exq = exp2f(fmaxf(p, -100.f)); // shift-invariant softmax
                ex[q] = (e + q) < e1 ? exq : 0.f;
            }
#pragma unroll
            for (int q = 0; q < 4; ++q) {
                s += ex[q];
#pragma unroll
                for (int j = 0; j < 4; ++j)
                    acc[j] = fmaf(ex[q], xj[q][j], acc[j]);
            }
        }
        float inv = __builtin_amdgcn_rcpf(s + 1e-16f);
        float v0 = fmaf(acc[0], inv, b4[0]);
        float v1 = fmaf(acc[1], inv, b4[1]);
        float v2 = fmaf(acc[2], inv, b4[2]);
        float v3 = fmaf(acc[3], inv, b4[3]);
        v0 = v0 > 0.f ? v0 : __expf(v0) - 1.f;   // ELU
        v1 = v1 > 0.f ? v1 : __expf(v1) - 1.f;
        v2 = v2 > 0.f ? v2 : __expf(v2) - 1.f;
        v3 = v3 > 0.f ? v3 : __expf(v3) - 1.f;
        uint2v o;
        o[0] = (unsigned)f2bs(v0) | ((unsigned)f2bs(v1) << 16);
        o[1] = (unsigned)f2bs(v2) | ((unsigned)f2bs(v3) << 16);
        *(uint2v*)(outb + n * 64 + c4) = o;
    }
}

// ---------------- 1x1 conv (MFMA): out = cat(b0,b1,b2)@W + bias + res ----------------
__global__ __launch_bounds__(256) void k_cc2(const __hip_bfloat16* __restrict__ b0,
        const __hip_bfloat16* __restrict__ b1, const __hip_bfloat16* __restrict__ b2,
        const __hip_bfloat16* __restrict__ pw, const float* __restrict__ bias,
        const float* __restrict__ resin, float* __restrict__ imgout,
        __hip_bfloat16* __restrict__ outb) {
    __shared__ i32x4 la[128 * 8];
    int t = threadIdx.x, lane = t & 63, wid = t >> 6;
    int n0 = blockIdx.x * 128;
    const __hip_bfloat16* brs[3] = {b0, b1, b2};
    const i32x4* wp4 = (const i32x4*)pw;
    f32x4 acc[2][4];
#pragma unroll
    for (int mi = 0; mi < 2; ++mi)
#pragma unroll
        for (int nt = 0; nt < 4; ++nt) acc[mi][nt] = (f32x4)0.0f;
#pragma unroll
    for (int br = 0; br < 3; ++br) {
        __syncthreads();
        const i32x4* Bg = (const i32x4*)brs[br] + n0 * 8;
        for (int idx = t; idx < 1024; idx += 256) {
            int r = idx >> 3, c = idx & 7;
            la[r * 8 + (c ^ (r & 7))] = Bg[idx];
        }
        __syncthreads();
        bf16x8 bf[4][2];
#pragma unroll
        for (int nt = 0; nt < 4; ++nt)
#pragma unroll
            for (int kk = 0; kk < 2; ++kk)
                bf[nt][kk] = __builtin_bit_cast(bf16x8,
                    wp4[(br * 8 + nt * 2 + kk) * 64 + lane]);
#pragma unroll
        for (int mi = 0; mi < 2; ++mi) {
            int row = wid * 32 + mi * 16 + (lane & 15);
#pragma unroll
            for (int kk = 0; kk < 2; ++kk) {
                bf16x8 a = __builtin_bit_cast(bf16x8,
                    la[row * 8 + (((kk << 2) | (lane >> 4)) ^ (row & 7))]);
#pragma unroll
                for (int nt = 0; nt < 4; ++nt)
                    acc[mi][nt] = mfma16(a, bf[nt][kk], acc[mi][nt]);
            }
        }
    }
#pragma unroll
    for (int mi = 0; mi < 2; ++mi)
#pragma unroll
        for (int nt = 0; nt < 4; ++nt) {
            int co = nt * 16 + (lane & 15);
            float bv = bias[co];
#pragma unroll
            for (int r = 0; r < 4; ++r) {
                int node = n0 + wid * 32 + mi * 16 + (lane >> 4) * 4 + r;
                float v = acc[mi][nt][r] + bv + resin[node * 64 + co];
                imgout[node * 64 + co] = v;
                outb[node * 64 + co] = __float2bfloat16(v);
            }
        }
}

// final stage: same GEMM, output NCHW fp32 via LDS transpose
__global__ __launch_bounds__(256) void k_ccfin(const __hip_bfloat16* __restrict__ b0,
        const __hip_bfloat16* __restrict__ b1, const __hip_bfloat16* __restrict__ b2,
        const __hip_bfloat16* __restrict__ pw, const float* __restrict__ bias,
        const float* __restrict__ resin, float* __restrict__ outp) {
    __shared__ i32x4 la[128 * 8];
    __shared__ float tt[64][132];
    int t = threadIdx.x, lane = t & 63, wid = t >> 6;
    int n0 = blockIdx.x * 128;
    const __hip_bfloat16* brs[3] = {b0, b1, b2};
    const i32x4* wp4 = (const i32x4*)pw;
    f32x4 acc[2][4];
#pragma unroll
    for (int mi = 0; mi < 2; ++mi)
#pragma unroll
        for (int nt = 0; nt < 4; ++nt) acc[mi][nt] = (f32x4)0.0f;
#pragma unroll
    for (int br = 0; br < 3; ++br) {
        __syncthreads();
        const i32x4* Bg = (const i32x4*)brs[br] + n0 * 8;
        for (int idx = t; idx < 1024; idx += 256) {
            int r = idx >> 3, c = idx & 7;
            la[r * 8 + (c ^ (r & 7))] = Bg[idx];
        }
        __syncthreads();
        bf16x8 bf[4][2];
#pragma unroll
        for (int nt = 0; nt < 4; ++nt)
#pragma unroll
            for (int kk = 0; kk < 2; ++kk)
                bf[nt][kk] = __builtin_bit_cast(bf16x8,
                    wp4[(br * 8 + nt * 2 + kk) * 64 + lane]);
#pragma unroll
        for (int mi = 0; mi < 2; ++mi) {
            int row = wid * 32 + mi * 16 + (lane & 15);
#pragma unroll
            for (int kk = 0; kk < 2; ++kk) {
                bf16x8 a = __builtin_bit_cast(bf16x8,
                    la[row * 8 + (((kk << 2) | (lane >> 4)) ^ (row & 7))]);
#pragma unroll
                for (int nt = 0; nt < 4; ++nt)
                    acc[mi][nt] = mfma16(a, bf[nt][kk], acc[mi][nt]);
            }
        }
    }
#pragma unroll
    for (int mi = 0; mi < 2; ++mi)
#pragma unroll
        for (int nt = 0; nt < 4; ++nt) {
            int co = nt * 16 + (lane & 15);
            float bv = bias[co];
#pragma unroll
            for (int r = 0; r < 4; ++r) {
                int nl = wid * 32 + mi * 16 + (lane >> 4) * 4 + r;
                tt[co][nl] = acc[mi][nt][r] + bv + resin[(n0 + nl) * 64 + co];
            }
        }
    __syncthreads();
    for (int u = t; u < 2048; u += 256) {
        int row = u >> 5;
        int col = (u & 31) * 4;
        f32x4 v = *(const f32x4*)&tt[row][col];
        *(f32x4*)(outp + row * HW + n0 + col) = v;
    }
}

// ---------------- 3x3 conv 64->64, channels-last, MFMA ----------------
template <int MODE>
__global__ __launch_bounds__(256) void k_conv(const __hip_bfloat16* __restrict__ inb,
        const __hip_bfloat16* __restrict__ wp, const float* __restrict__ bias,
        const float* __restrict__ pa, float* __restrict__ img,
        __hip_bfloat16* __restrict__ outb) {
    __shared__ i32x4 la[130 * 8];
    int t = threadIdx.x, lane = t & 63, wid = t >> 6;
    int y = blockIdx.x >> 1, x0 = (blockIdx.x & 1) << 7;
    f32x4 acc[2][4];
#pragma unroll
    for (int mi = 0; mi < 2; ++mi)
#pragma unroll
        for (int nt = 0; nt < 4; ++nt) acc[mi][nt] = (f32x4)0.0f;
    const i32x4* ing = (const i32x4*)inb;
#pragma unroll
    for (int dy = 0; dy < 3; ++dy) {
        int sy = y + dy - 1;
        bool rowok = (sy >= 0) && (sy < 256);
        __syncthreads();
        for (int idx = t; idx < 1040; idx += 256) {
            int r = idx >> 3, c = idx & 7;
            int sx = x0 - 1 + r;
            i32x4 v = (i32x4)0;
            if (rowok && sx >= 0 && sx < 256) v = ing[(sy * 256 + sx) * 8 + c];
            la[r * 8 + (c ^ (r & 7))] = v;
        }
        __syncthreads();
#pragma unroll
        for (int dx = 0; dx < 3; ++dx) {
            const i32x4* wpt = (const i32x4*)wp + (dy * 3 + dx) * 512 + lane;
            bf16x8 b[4][2];
#pragma unroll
            for (int nt = 0; nt < 4; ++nt)
#pragma unroll
                for (int kk = 0; kk < 2; ++kk)
                    b[nt][kk] = __builtin_bit_cast(bf16x8, wpt[(nt * 2 + kk) * 64]);
#pragma unroll
            for (int mi = 0; mi < 2; ++mi) {
                int row = dx + wid * 32 + mi * 16 + (lane & 15);
#pragma unroll
                for (int kk = 0; kk < 2; ++kk) {
                    bf16x8 a = __builtin_bit_cast(bf16x8,
                        la[row * 8 + (((kk << 2) | (lane >> 4)) ^ (row & 7))]);
#pragma unroll
                    for (int nt = 0; nt < 4; ++nt)
                        acc[mi][nt] = mfma16(a, b[nt][kk], acc[mi][nt]);
                }
            }
        }
    }
    int pbase = y * 256 + x0 + wid * 32 + (lane >> 4) * 4;
    float aprelu = (MODE == 0) ? pa[0] : 0.f;
#pragma unroll
    for (int mi = 0; mi < 2; ++mi)
#pragma unroll
        for (int nt = 0; nt < 4; ++nt) {
            int co = nt * 16 + (lane & 15);
            float bv = bias[co];
#pragma unroll
            for (int r = 0; r < 4; ++r) {
                int pix = pbase + mi * 16 + r;
                float v = acc[mi][nt][r] + bv;
                if (MODE == 0) {
                    v = v >= 0.f ? v : aprelu * v;
                    outb[pix * 64 + co] = __float2bfloat16(v);
                } else {
                    v += img[pix * 64 + co];
                    img[pix * 64 + co] = v;
                    outb[pix * 64 + co] = __float2bfloat16(v);
                }
            }
        }
}

// ---------------- host ----------------
extern "C" void kernel_launch(void* const* d_in, const int* in_sizes, int n_in,
                              void* d_out, int out_size, void* d_ws, size_t ws_size,
                              hipStream_t stream) {
    const float* x    = (const float*)d_in[0];
    const int*   ei   = (const int*)d_in[1];
    const float* gWl  = (const float*)d_in[2];   // [27][64][64]
    const float* gWr  = (const float*)d_in[3];
    const float* gatt = (const float*)d_in[4];   // [27][64]
    const float* gb   = (const float*)d_in[5];   // [27][64]
    const float* ccw  = (const float*)d_in[6];   // [3][64][192]
    const float* ccb  = (const float*)d_in[7];   // [3][64]
    const float* rbw  = (const float*)d_in[8];   // [16][64][64][3][3]
    const float* rbb  = (const float*)d_in[9];   // [16][64]
    const float* rba  = (const float*)d_in[10];  // [8]
    float* outp = (float*)d_out;

    float* wsf = (float*)d_ws;
    float* xn  = wsf;            // [N,64] fp32 stage-0 residual
    float* xrs = xn  + NC;       // slot reused as bf16 XRb
    float* img = xrs + NC;       // [N,64] fp32 running image
    __hip_bfloat16* xrb  = (__hip_bfloat16*)xrs;
    __hip_bfloat16* xlb  = (__hip_bfloat16*)(img + NC);
    __hip_bfloat16* xb   = xlb + NC;
    __hip_bfloat16* t0b  = xb  + NC;
    __hip_bfloat16* cvb  = t0b + NC;
    __hip_bfloat16* b0b  = cvb + NC;
    __hip_bfloat16* b1b  = b0b + NC;
    __hip_bfloat16* b2b  = b1b + NC;
    __hip_bfloat16* wpkc = b2b + NC;        // 589824
    __hip_bfloat16* wpkm = wpkc + 589824;   // 221184
    __hip_bfloat16* ccpk = wpkm + 221184;   // 36864
    int* ioff  = (int*)(ccpk + 36864);
    int* icnt  = ioff + (N_NODES + 1);
    int* icur  = icnt + N_NODES;
    int* icsr  = icur + N_NODES;            // NE
    int* iperm = icsr + NE;                 // N
    int* icnt2 = iperm + N_NODES;           // N
    int* ioff2 = icnt2 + N_NODES;           // N+1
    int* icsr2 = ioff2 + (N_NODES + 1);     // NE
    int* dh    = icsr2 + NE;                // 64
    int* dbase = dh + 64;                   // 64
    int* dcur  = dbase + 64;                // 64

    const int* srcA = ei;
    const int* dstA = ei + NE;

    hipMemsetAsync(icnt, 0, N_NODES * sizeof(int), stream);
    hipMemsetAsync(dh, 0, 64 * sizeof(int), stream);
    k_hist<<<NE / 256, 256, 0, stream>>>(dstA, icnt);
    k_scan<<<1, 1024, 0, stream>>>(icnt, ioff);
    hipMemcpyAsync(icur, ioff, N_NODES * sizeof(int), hipMemcpyDeviceToDevice, stream);
    k_fill<<<NE / 256, 256, 0, stream>>>(srcA, dstA, icur, icsr);
    // degree sort -> perm, permuted CSR
    k_dhist<<<N_NODES / 256, 256, 0, stream>>>(icnt, dh);
    k_dscan<<<1, 64, 0, stream>>>(dh, dbase);
    hipMemcpyAsync(dcur, dbase, 64 * sizeof(int), hipMemcpyDeviceToDevice, stream);
    k_dscatter<<<N_NODES / 256, 256, 0, stream>>>(icnt, dcur, iperm);
    k_permdeg<<<N_NODES / 256, 256, 0, stream>>>(iperm, icnt, icnt2);
    k_scan<<<1, 1024, 0, stream>>>(icnt2, ioff2);
    k_csr2<<<N_NODES / 256, 256, 0, stream>>>(iperm, icnt, ioff, ioff2, icsr, icsr2);
    // weight packs + input convert
    k_cvpack<<<2304, 256, 0, stream>>>(rbw, wpkc);
    k_mmpack<<<864, 256, 0, stream>>>(gWl, gWr, wpkm);
    k_ccpack<<<144, 256, 0, stream>>>(ccw, ccpk);
    k_init<<<1024, 256, 0, stream>>>(x, xn, xb);

    __hip_bfloat16* brsb[3] = {b0b, b1b, b2b};
    for (int st = 0; st < 3; ++st) {
        for (int mb = 0; mb < 3; ++mb) {
            const __hip_bfloat16* lin = xb;
            for (int l = 0; l < 3; ++l) {
                int lay = (st * 3 + mb) * 3 + l;
                k_mm<<<N_NODES / 128, 256, 0, stream>>>(lin, wpkm + lay * 8192, xlb, xrb);
                const float* at = gatt + lay * 64;
                const float* bb = gb + lay * 64;
                __hip_bfloat16* dst = (l < 2) ? t0b : brsb[mb];
                k_gat<<<2048, 256, 0, stream>>>(xlb, xrb, at, bb, iperm, ioff2,
                                                icsr2, dst);
                lin = t0b;
            }
        }
        const float* resin = (st == 0) ? xn : img;
        if (st == 2) {
            k_ccfin<<<N_NODES / 128, 256, 0, stream>>>(b0b, b1b, b2b,
                ccpk + 2 * 12288, ccb + 128, resin, outp);
        } else {
            k_cc2<<<N_NODES / 128, 256, 0, stream>>>(b0b, b1b, b2b,
                ccpk + st * 12288, ccb + st * 64, resin, img, xb);
            for (int bk = 0; bk < 4; ++bk) {
                int cv = (st * 4 + bk) * 2;
                k_conv<0><<<512, 256, 0, stream>>>(xb, wpkc + (size_t)cv * 36864,
                    rbb + cv * 64, rba + st * 4 + bk, nullptr, cvb);
                k_conv<1><<<512, 256, 0, stream>>>(cvb, wpkc + (size_t)(cv + 1) * 36864,
                    rbb + (cv + 1) * 64, nullptr, img, xb);
            }
        }
    }
}

// Round 8
// 1306.973 us; speedup vs baseline: 1.4261x; 1.4261x over previous
//
#include <hip/hip_runtime.h>
#include <hip/hip_bf16.h>
#include <math.h>

#define N_NODES 65536
#define HW      65536
#define NE      524288
#define NC      (N_NODES * 64)

typedef __bf16 bf16x8 __attribute__((ext_vector_type(8)));
typedef float  f32x4  __attribute__((ext_vector_type(4)));
typedef float  f32x2  __attribute__((ext_vector_type(2)));
typedef int    i32x4  __attribute__((ext_vector_type(4)));
typedef unsigned int uint2v __attribute__((ext_vector_type(2)));

static __device__ __forceinline__ f32x4 mfma16(bf16x8 a, bf16x8 b, f32x4 c) {
    return __builtin_amdgcn_mfma_f32_16x16x32_bf16(a, b, c, 0, 0, 0);
}

static __device__ __forceinline__ unsigned short f2bs(float f) {
    return __builtin_bit_cast(unsigned short, __float2bfloat16(f));
}

static __device__ __forceinline__ void unpack4(uint2v xw, f32x4& xj) {
    xj[0] = __builtin_bit_cast(float, xw[0] << 16);
    xj[1] = __builtin_bit_cast(float, xw[0] & 0xffff0000u);
    xj[2] = __builtin_bit_cast(float, xw[1] << 16);
    xj[3] = __builtin_bit_cast(float, xw[1] & 0xffff0000u);
}

static __device__ __forceinline__ void unpack_fp8(unsigned int w, f32x4& xj) {
    f32x2 lo = __builtin_amdgcn_cvt_pk_f32_fp8((int)w, false);
    f32x2 hi = __builtin_amdgcn_cvt_pk_f32_fp8((int)w, true);
    xj[0] = lo[0]; xj[1] = lo[1]; xj[2] = hi[0]; xj[3] = hi[1];
}

// ---------------- CSR build ----------------
__global__ void k_hist(const int* __restrict__ dstA, int* __restrict__ cnt) {
    int e = blockIdx.x * 256 + threadIdx.x;
    if (e < NE) atomicAdd(&cnt[dstA[e]], 1);
}

__global__ void k_scan(const int* __restrict__ cnt, int* __restrict__ off) {
    __shared__ int sums[1024];
    int t = threadIdx.x;
    int base = t * 64;
    int s = 0;
    for (int i = 0; i < 64; ++i) s += cnt[base + i];
    sums[t] = s;
    __syncthreads();
    for (int d = 1; d < 1024; d <<= 1) {
        int v = (t >= d) ? sums[t - d] : 0;
        __syncthreads();
        sums[t] += v;
        __syncthreads();
    }
    int run = sums[t] - s;  // exclusive prefix
    for (int i = 0; i < 64; ++i) { off[base + i] = run; run += cnt[base + i]; }
    if (t == 1023) off[N_NODES] = run;
}

__global__ void k_fill(const int* __restrict__ srcA, const int* __restrict__ dstA,
                       int* __restrict__ cur, int* __restrict__ csr) {
    int e = blockIdx.x * 256 + threadIdx.x;
    if (e < NE) {
        int p = atomicAdd(&cur[dstA[e]], 1);
        csr[p] = srcA[e];
    }
}

// ---------------- weight packing (MFMA fragment order) ----------------
// conv: rb_w [16][co][ci][3][3] -> [cv][tap][nt][kk][lane][8] bf16
__global__ void k_cvpack(const float* __restrict__ w, __hip_bfloat16* __restrict__ d) {
    int idx = blockIdx.x * 256 + threadIdx.x;
    if (idx >= 589824) return;
    int j = idx & 7, lane = (idx >> 3) & 63, r = idx >> 9;
    int kk = r & 1; r >>= 1;
    int nt = r & 3; r >>= 2;
    int tap = r % 9, cv = r / 9;
    int co = nt * 16 + (lane & 15);
    int ci = kk * 32 + (lane >> 4) * 8 + j;
    d[idx] = __float2bfloat16(w[((cv * 64 + co) * 64 + ci) * 9 + tap]);
}

// gat mm: gWl/gWr [27][ci][co] -> [lay][side][nt][kk][lane][8] bf16
__global__ void k_mmpack(const float* __restrict__ Wl, const float* __restrict__ Wr,
                         __hip_bfloat16* __restrict__ d) {
    int idx = blockIdx.x * 256 + threadIdx.x;
    if (idx >= 221184) return;
    int j = idx & 7, lane = (idx >> 3) & 63, r = idx >> 9;
    int kk = r & 1; r >>= 1;
    int nt = r & 3; r >>= 2;
    int side = r & 1, lay = r >> 1;
    int co = nt * 16 + (lane & 15);
    int ci = kk * 32 + (lane >> 4) * 8 + j;
    const float* W = side ? Wr : Wl;
    d[idx] = __float2bfloat16(W[lay * 4096 + ci * 64 + co]);
}

// cc_w [3][o=64][k=192] -> [st][br][nt][kk][lane][8] bf16
__global__ void k_ccpack(const float* __restrict__ w, __hip_bfloat16* __restrict__ d) {
    int idx = blockIdx.x * 256 + threadIdx.x;
    if (idx >= 36864) return;
    int j = idx & 7;
    int u = idx >> 3;
    int lane = u & 63;
    int f = (u >> 6) & 7;
    int sb = u >> 9;
    int kk = f & 1, nt = f >> 1;
    int br = sb % 3, st = sb / 3;
    int k = br * 64 + kk * 32 + (lane >> 4) * 8 + j;
    int co = nt * 16 + (lane & 15);
    d[idx] = __float2bfloat16(w[st * 12288 + co * 192 + k]);
}

// ---------------- initial NCHW -> [N,64] fp32 + bf16 ----------------
__global__ void k_init(const float* __restrict__ img, float* __restrict__ xn,
                       __hip_bfloat16* __restrict__ xb) {
    __shared__ float tile[64][65];
    int nb = blockIdx.x * 64;
    for (int idx = threadIdx.x; idx < 4096; idx += 256) {
        int c = idx >> 6, n = idx & 63;
        tile[c][n] = img[c * HW + nb + n];
    }
    __syncthreads();
    for (int idx = threadIdx.x; idx < 4096; idx += 256) {
        int n = idx >> 6, c = idx & 63;
        float v = tile[c][n];
        xn[(nb + n) * 64 + c] = v;
        xb[(nb + n) * 64 + c] = __float2bfloat16(v);
    }
}

// ---------------- MFMA dual matmul: XL8 = fp8(X@Wl), XRb = bf16(X@Wr) ----------------
// side-0 result is bounced through LDS so 8 consecutive channels land in one
// thread for fp8 packing (gather-side layout [node][ch] byte-contiguous).
__global__ __launch_bounds__(256) void k_mm(const __hip_bfloat16* __restrict__ Xb,
        const __hip_bfloat16* __restrict__ pw, unsigned char* __restrict__ XL8,
        __hip_bfloat16* __restrict__ XRb) {
    __shared__ char smem[17408];
    i32x4* la = (i32x4*)smem;
    int t = threadIdx.x, lane = t & 63, wid = t >> 6;
    int n0 = blockIdx.x * 128;
    const i32x4* Xg = (const i32x4*)Xb + n0 * 8;
    for (int idx = t; idx < 1024; idx += 256) {
        int r = idx >> 3, c = idx & 7;
        la[r * 8 + (c ^ (r & 7))] = Xg[idx];
    }
    int side = wid & 1, rh = wid >> 1;
    const i32x4* wpt = (const i32x4*)pw + side * 512 + lane;
    f32x4 acc[4][4];
#pragma unroll
    for (int mi = 0; mi < 4; ++mi)
#pragma unroll
        for (int nt = 0; nt < 4; ++nt) acc[mi][nt] = (f32x4)0.0f;
    bf16x8 b[4][2];
#pragma unroll
    for (int nt = 0; nt < 4; ++nt)
#pragma unroll
        for (int kk = 0; kk < 2; ++kk)
            b[nt][kk] = __builtin_bit_cast(bf16x8, wpt[(nt * 2 + kk) * 64]);
    __syncthreads();
#pragma unroll
    for (int mi = 0; mi < 4; ++mi) {
        int row = rh * 64 + mi * 16 + (lane & 15);
#pragma unroll
        for (int kk = 0; kk < 2; ++kk) {
            bf16x8 a = __builtin_bit_cast(bf16x8,
                la[row * 8 + (((kk << 2) | (lane >> 4)) ^ (row & 7))]);
#pragma unroll
            for (int nt = 0; nt < 4; ++nt)
                acc[mi][nt] = mfma16(a, b[nt][kk], acc[mi][nt]);
        }
    }
    __syncthreads();                      // la consumed; repurpose as bf16 stage
    unsigned short* ls = (unsigned short*)smem;
    if (side == 0) {
#pragma unroll
        for (int mi = 0; mi < 4; ++mi)
#pragma unroll
            for (int nt = 0; nt < 4; ++nt) {
                int co = nt * 16 + (lane & 15);
#pragma unroll
                for (int r = 0; r < 4; ++r) {
                    int row = rh * 64 + mi * 16 + (lane >> 4) * 4 + r;
                    ls[row * 68 + co] = f2bs(acc[mi][nt][r]);
                }
            }
    } else {
#pragma unroll
        for (int mi = 0; mi < 4; ++mi)
#pragma unroll
            for (int nt = 0; nt < 4; ++nt) {
                int co = nt * 16 + (lane & 15);
#pragma unroll
                for (int r = 0; r < 4; ++r) {
                    int node = n0 + rh * 64 + mi * 16 + (lane >> 4) * 4 + r;
                    XRb[node * 64 + co] = __float2bfloat16(acc[mi][nt][r]);
                }
            }
    }
    __syncthreads();
    for (int u = t; u < 1024; u += 256) {     // 128 nodes x 8 channel-octs
        int node = u >> 3, oct = u & 7;
        const unsigned short* p = ls + node * 68 + oct * 8;
        uint2v w0 = *(const uint2v*)p;
        uint2v w1 = *(const uint2v*)(p + 4);
        float f0 = __builtin_bit_cast(float, w0[0] << 16);
        float f1 = __builtin_bit_cast(float, w0[0] & 0xffff0000u);
        float f2 = __builtin_bit_cast(float, w0[1] << 16);
        float f3 = __builtin_bit_cast(float, w0[1] & 0xffff0000u);
        float f4 = __builtin_bit_cast(float, w1[0] << 16);
        float f5 = __builtin_bit_cast(float, w1[0] & 0xffff0000u);
        float f6 = __builtin_bit_cast(float, w1[1] << 16);
        float f7 = __builtin_bit_cast(float, w1[1] & 0xffff0000u);
        int v0 = 0, v1 = 0;
        v0 = __builtin_amdgcn_cvt_pk_fp8_f32(f0, f1, v0, false);
        v0 = __builtin_amdgcn_cvt_pk_fp8_f32(f2, f3, v0, true);
        v1 = __builtin_amdgcn_cvt_pk_fp8_f32(f4, f5, v1, false);
        v1 = __builtin_amdgcn_cvt_pk_fp8_f32(f6, f7, v1, true);
        uint2v o;
        o[0] = (unsigned)v0;
        o[1] = (unsigned)v1;
        *(uint2v*)(XL8 + (size_t)(n0 + node) * 64 + oct * 8) = o;
    }
}

// ---------------- GAT edge phase (fp8 gather) ----------------
// 16-lane group owns one node (4 ch/lane). Per-head softmax = quad reduce only.
// fp8 XL: 64B/edge gather, footprint 4.2MB fits one XCD L2.
__global__ __launch_bounds__(256) void k_gat(const unsigned char* __restrict__ XL8,
        const __hip_bfloat16* __restrict__ XRb, const float* __restrict__ att64,
        const float* __restrict__ bias, const int* __restrict__ off,
        const int* __restrict__ csr, __hip_bfloat16* __restrict__ outb) {
    __shared__ int csr_c[320];
    int tid = threadIdx.x;
    int lane = tid & 63;
    int g = (lane >> 4) & 3;
    int c4 = (lane & 15) << 2;
    int nblk = blockIdx.x * 32;
    int cbase = off[nblk];
    int ccnt = min(off[nblk + 32] - cbase, 320);
    for (int idx = tid; idx < ccnt; idx += 256) csr_c[idx] = csr[cbase + idx];
    __syncthreads();
    const float LOG2E = 1.44269504089f;
    f32x4 a4 = *(const f32x4*)(att64 + c4);
#pragma unroll
    for (int j = 0; j < 4; ++j) a4[j] *= LOG2E;
    f32x4 b4 = *(const f32x4*)(bias + c4);
    int base = nblk + ((tid >> 6) << 3) + g * 2;   // 2 consecutive nodes per group
#pragma unroll
    for (int nn = 0; nn < 2; ++nn) {
        int n = base + nn;
        int e0 = off[n], e1 = off[n + 1];
        uint2v xw = *(const uint2v*)(XRb + n * 64 + c4);
        f32x4 xi;
        unpack4(xw, xi);
        float s = 0.f;
        f32x4 acc = (f32x4)0.0f;
        int rounds = (e1 - e0 + 1) >> 1;
        int e = e0;
        for (int i = 0; i < rounds; ++i, e += 2) {
            bool aB = (e + 1) < e1;
            int eB = aB ? e + 1 : e;
            int rA = e - cbase, rB = eB - cbase;
            int sA = (rA < ccnt) ? csr_c[rA] : csr[e];
            int sB = (rB < ccnt) ? csr_c[rB] : csr[eB];
            unsigned int wA = *(const unsigned int*)(XL8 + (size_t)sA * 64 + c4);
            unsigned int wB = *(const unsigned int*)(XL8 + (size_t)sB * 64 + c4);
            f32x4 xjA, xjB;
            unpack_fp8(wA, xjA);
            unpack_fp8(wB, xjB);
            float pA = 0.f, pB = 0.f;
#pragma unroll
            for (int j = 0; j < 4; ++j) {
                float vA = xi[j] + xjA[j];
                vA = fmaxf(vA, 0.2f * vA);       // leaky_relu(0.2)
                pA = fmaf(vA, a4[j], pA);
                float vB = xi[j] + xjB[j];
                vB = fmaxf(vB, 0.2f * vB);
                pB = fmaf(vB, a4[j], pB);
            }
            pA += __shfl_xor(pA, 1);
            pA += __shfl_xor(pA, 2);             // per-head logit (quad reduce)
            pB += __shfl_xor(pB, 1);
            pB += __shfl_xor(pB, 2);
            float exA = exp2f(fmaxf(pA, -100.f));    // shift-invariant softmax
            float exB = exp2f(fmaxf(pB, -100.f));
            exB = aB ? exB : 0.f;
            s += exA + exB;
#pragma unroll
            for (int j = 0; j < 4; ++j)
                acc[j] = fmaf(exA, xjA[j], fmaf(exB, xjB[j], acc[j]));
        }
        float inv = __builtin_amdgcn_rcpf(s + 1e-16f);
        float v0 = fmaf(acc[0], inv, b4[0]);
        float v1 = fmaf(acc[1], inv, b4[1]);
        float v2 = fmaf(acc[2], inv, b4[2]);
        float v3 = fmaf(acc[3], inv, b4[3]);
        v0 = v0 > 0.f ? v0 : __expf(v0) - 1.f;   // ELU
        v1 = v1 > 0.f ? v1 : __expf(v1) - 1.f;
        v2 = v2 > 0.f ? v2 : __expf(v2) - 1.f;
        v3 = v3 > 0.f ? v3 : __expf(v3) - 1.f;
        uint2v o;
        o[0] = (unsigned)f2bs(v0) | ((unsigned)f2bs(v1) << 16);
        o[1] = (unsigned)f2bs(v2) | ((unsigned)f2bs(v3) << 16);
        *(uint2v*)(outb + n * 64 + c4) = o;
    }
}

// ---------------- 1x1 conv (MFMA): out = cat(b0,b1,b2)@W + bias + res ----------------
__global__ __launch_bounds__(256) void k_cc2(const __hip_bfloat16* __restrict__ b0,
        const __hip_bfloat16* __restrict__ b1, const __hip_bfloat16* __restrict__ b2,
        const __hip_bfloat16* __restrict__ pw, const float* __restrict__ bias,
        const float* __restrict__ resin, float* __restrict__ imgout,
        __hip_bfloat16* __restrict__ outb) {
    __shared__ i32x4 la[128 * 8];
    int t = threadIdx.x, lane = t & 63, wid = t >> 6;
    int n0 = blockIdx.x * 128;
    const __hip_bfloat16* brs[3] = {b0, b1, b2};
    const i32x4* wp4 = (const i32x4*)pw;
    f32x4 acc[2][4];
#pragma unroll
    for (int mi = 0; mi < 2; ++mi)
#pragma unroll
        for (int nt = 0; nt < 4; ++nt) acc[mi][nt] = (f32x4)0.0f;
#pragma unroll
    for (int br = 0; br < 3; ++br) {
        __syncthreads();
        const i32x4* Bg = (const i32x4*)brs[br] + n0 * 8;
        for (int idx = t; idx < 1024; idx += 256) {
            int r = idx >> 3, c = idx & 7;
            la[r * 8 + (c ^ (r & 7))] = Bg[idx];
        }
        __syncthreads();
        bf16x8 bf[4][2];
#pragma unroll
        for (int nt = 0; nt < 4; ++nt)
#pragma unroll
            for (int kk = 0; kk < 2; ++kk)
                bf[nt][kk] = __builtin_bit_cast(bf16x8,
                    wp4[(br * 8 + nt * 2 + kk) * 64 + lane]);
#pragma unroll
        for (int mi = 0; mi < 2; ++mi) {
            int row = wid * 32 + mi * 16 + (lane & 15);
#pragma unroll
            for (int kk = 0; kk < 2; ++kk) {
                bf16x8 a = __builtin_bit_cast(bf16x8,
                    la[row * 8 + (((kk << 2) | (lane >> 4)) ^ (row & 7))]);
#pragma unroll
                for (int nt = 0; nt < 4; ++nt)
                    acc[mi][nt] = mfma16(a, bf[nt][kk], acc[mi][nt]);
            }
        }
    }
#pragma unroll
    for (int mi = 0; mi < 2; ++mi)
#pragma unroll
        for (int nt = 0; nt < 4; ++nt) {
            int co = nt * 16 + (lane & 15);
            float bv = bias[co];
#pragma unroll
            for (int r = 0; r < 4; ++r) {
                int node = n0 + wid * 32 + mi * 16 + (lane >> 4) * 4 + r;
                float v = acc[mi][nt][r] + bv + resin[node * 64 + co];
                imgout[node * 64 + co] = v;
                outb[node * 64 + co] = __float2bfloat16(v);
            }
        }
}

// final stage: same GEMM, output NCHW fp32 via LDS transpose
__global__ __launch_bounds__(256) void k_ccfin(const __hip_bfloat16* __restrict__ b0,
        const __hip_bfloat16* __restrict__ b1, const __hip_bfloat16* __restrict__ b2,
        const __hip_bfloat16* __restrict__ pw, const float* __restrict__ bias,
        const float* __restrict__ resin, float* __restrict__ outp) {
    __shared__ i32x4 la[128 * 8];
    __shared__ float tt[64][132];
    int t = threadIdx.x, lane = t & 63, wid = t >> 6;
    int n0 = blockIdx.x * 128;
    const __hip_bfloat16* brs[3] = {b0, b1, b2};
    const i32x4* wp4 = (const i32x4*)pw;
    f32x4 acc[2][4];
#pragma unroll
    for (int mi = 0; mi < 2; ++mi)
#pragma unroll
        for (int nt = 0; nt < 4; ++nt) acc[mi][nt] = (f32x4)0.0f;
#pragma unroll
    for (int br = 0; br < 3; ++br) {
        __syncthreads();
        const i32x4* Bg = (const i32x4*)brs[br] + n0 * 8;
        for (int idx = t; idx < 1024; idx += 256) {
            int r = idx >> 3, c = idx & 7;
            la[r * 8 + (c ^ (r & 7))] = Bg[idx];
        }
        __syncthreads();
        bf16x8 bf[4][2];
#pragma unroll
        for (int nt = 0; nt < 4; ++nt)
#pragma unroll
            for (int kk = 0; kk < 2; ++kk)
                bf[nt][kk] = __builtin_bit_cast(bf16x8,
                    wp4[(br * 8 + nt * 2 + kk) * 64 + lane]);
#pragma unroll
        for (int mi = 0; mi < 2; ++mi) {
            int row = wid * 32 + mi * 16 + (lane & 15);
#pragma unroll
            for (int kk = 0; kk < 2; ++kk) {
                bf16x8 a = __builtin_bit_cast(bf16x8,
                    la[row * 8 + (((kk << 2) | (lane >> 4)) ^ (row & 7))]);
#pragma unroll
                for (int nt = 0; nt < 4; ++nt)
                    acc[mi][nt] = mfma16(a, bf[nt][kk], acc[mi][nt]);
            }
        }
    }
#pragma unroll
    for (int mi = 0; mi < 2; ++mi)
#pragma unroll
        for (int nt = 0; nt < 4; ++nt) {
            int co = nt * 16 + (lane & 15);
            float bv = bias[co];
#pragma unroll
            for (int r = 0; r < 4; ++r) {
                int nl = wid * 32 + mi * 16 + (lane >> 4) * 4 + r;
                tt[co][nl] = acc[mi][nt][r] + bv + resin[(n0 + nl) * 64 + co];
            }
        }
    __syncthreads();
    for (int u = t; u < 2048; u += 256) {
        int row = u >> 5;
        int col = (u & 31) * 4;
        f32x4 v = *(const f32x4*)&tt[row][col];
        *(f32x4*)(outp + row * HW + n0 + col) = v;
    }
}

// ---------------- 3x3 conv 64->64, channels-last, MFMA ----------------
template <int MODE>
__global__ __launch_bounds__(256) void k_conv(const __hip_bfloat16* __restrict__ inb,
        const __hip_bfloat16* __restrict__ wp, const float* __restrict__ bias,
        const float* __restrict__ pa, float* __restrict__ img,
        __hip_bfloat16* __restrict__ outb) {
    __shared__ i32x4 la[130 * 8];
    int t = threadIdx.x, lane = t & 63, wid = t >> 6;
    int y = blockIdx.x >> 1, x0 = (blockIdx.x & 1) << 7;
    f32x4 acc[2][4];
#pragma unroll
    for (int mi = 0; mi < 2; ++mi)
#pragma unroll
        for (int nt = 0; nt < 4; ++nt) acc[mi][nt] = (f32x4)0.0f;
    const i32x4* ing = (const i32x4*)inb;
#pragma unroll
    for (int dy = 0; dy < 3; ++dy) {
        int sy = y + dy - 1;
        bool rowok = (sy >= 0) && (sy < 256);
        __syncthreads();
        for (int idx = t; idx < 1040; idx += 256) {
            int r = idx >> 3, c = idx & 7;
            int sx = x0 - 1 + r;
            i32x4 v = (i32x4)0;
            if (rowok && sx >= 0 && sx < 256) v = ing[(sy * 256 + sx) * 8 + c];
            la[r * 8 + (c ^ (r & 7))] = v;
        }
        __syncthreads();
#pragma unroll
        for (int dx = 0; dx < 3; ++dx) {
            const i32x4* wpt = (const i32x4*)wp + (dy * 3 + dx) * 512 + lane;
            bf16x8 b[4][2];
#pragma unroll
            for (int nt = 0; nt < 4; ++nt)
#pragma unroll
                for (int kk = 0; kk < 2; ++kk)
                    b[nt][kk] = __builtin_bit_cast(bf16x8, wpt[(nt * 2 + kk) * 64]);
#pragma unroll
            for (int mi = 0; mi < 2; ++mi) {
                int row = dx + wid * 32 + mi * 16 + (lane & 15);
#pragma unroll
                for (int kk = 0; kk < 2; ++kk) {
                    bf16x8 a = __builtin_bit_cast(bf16x8,
                        la[row * 8 + (((kk << 2) | (lane >> 4)) ^ (row & 7))]);
#pragma unroll
                    for (int nt = 0; nt < 4; ++nt)
                        acc[mi][nt] = mfma16(a, b[nt][kk], acc[mi][nt]);
                }
            }
        }
    }
    int pbase = y * 256 + x0 + wid * 32 + (lane >> 4) * 4;
    float aprelu = (MODE == 0) ? pa[0] : 0.f;
#pragma unroll
    for (int mi = 0; mi < 2; ++mi)
#pragma unroll
        for (int nt = 0; nt < 4; ++nt) {
            int co = nt * 16 + (lane & 15);
            float bv = bias[co];
#pragma unroll
            for (int r = 0; r < 4; ++r) {
                int pix = pbase + mi * 16 + r;
                float v = acc[mi][nt][r] + bv;
                if (MODE == 0) {
                    v = v >= 0.f ? v : aprelu * v;
                    outb[pix * 64 + co] = __float2bfloat16(v);
                } else {
                    v += img[pix * 64 + co];
                    img[pix * 64 + co] = v;
                    outb[pix * 64 + co] = __float2bfloat16(v);
                }
            }
        }
}

// ---------------- host ----------------
extern "C" void kernel_launch(void* const* d_in, const int* in_sizes, int n_in,
                              void* d_out, int out_size, void* d_ws, size_t ws_size,
                              hipStream_t stream) {
    const float* x    = (const float*)d_in[0];
    const int*   ei   = (const int*)d_in[1];
    const float* gWl  = (const float*)d_in[2];   // [27][64][64]
    const float* gWr  = (const float*)d_in[3];
    const float* gatt = (const float*)d_in[4];   // [27][64]
    const float* gb   = (const float*)d_in[5];   // [27][64]
    const float* ccw  = (const float*)d_in[6];   // [3][64][192]
    const float* ccb  = (const float*)d_in[7];   // [3][64]
    const float* rbw  = (const float*)d_in[8];   // [16][64][64][3][3]
    const float* rbb  = (const float*)d_in[9];   // [16][64]
    const float* rba  = (const float*)d_in[10];  // [8]
    float* outp = (float*)d_out;

    float* wsf = (float*)d_ws;
    float* xn  = wsf;            // [N,64] fp32 stage-0 residual
    float* xrs = xn  + NC;       // slot reused as bf16 XRb
    float* img = xrs + NC;       // [N,64] fp32 running image
    __hip_bfloat16* xrb  = (__hip_bfloat16*)xrs;
    unsigned char*  xl8  = (unsigned char*)(img + NC);     // NC bytes fp8 XL
    __hip_bfloat16* xb   = (__hip_bfloat16*)(img + NC) + NC;
    __hip_bfloat16* t0b  = xb  + NC;
    __hip_bfloat16* cvb  = t0b + NC;
    __hip_bfloat16* b0b  = cvb + NC;
    __hip_bfloat16* b1b  = b0b + NC;
    __hip_bfloat16* b2b  = b1b + NC;
    __hip_bfloat16* wpkc = b2b + NC;        // 589824
    __hip_bfloat16* wpkm = wpkc + 589824;   // 221184
    __hip_bfloat16* ccpk = wpkm + 221184;   // 36864
    int* ioff = (int*)(ccpk + 36864);
    int* icnt = ioff + (N_NODES + 1);
    int* icur = icnt + N_NODES;
    int* icsr = icur + N_NODES;             // NE

    const int* srcA = ei;
    const int* dstA = ei + NE;

    hipMemsetAsync(icnt, 0, N_NODES * sizeof(int), stream);
    k_hist<<<NE / 256, 256, 0, stream>>>(dstA, icnt);
    k_scan<<<1, 1024, 0, stream>>>(icnt, ioff);
    hipMemcpyAsync(icur, ioff, N_NODES * sizeof(int), hipMemcpyDeviceToDevice, stream);
    k_fill<<<NE / 256, 256, 0, stream>>>(srcA, dstA, icur, icsr);
    k_cvpack<<<2304, 256, 0, stream>>>(rbw, wpkc);
    k_mmpack<<<864, 256, 0, stream>>>(gWl, gWr, wpkm);
    k_ccpack<<<144, 256, 0, stream>>>(ccw, ccpk);
    k_init<<<1024, 256, 0, stream>>>(x, xn, xb);

    __hip_bfloat16* brsb[3] = {b0b, b1b, b2b};
    for (int st = 0; st < 3; ++st) {
        for (int mb = 0; mb < 3; ++mb) {
            const __hip_bfloat16* lin = xb;
            for (int l = 0; l < 3; ++l) {
                int lay = (st * 3 + mb) * 3 + l;
                k_mm<<<N_NODES / 128, 256, 0, stream>>>(lin, wpkm + lay * 8192, xl8, xrb);
                const float* at = gatt + lay * 64;
                const float* bb = gb + lay * 64;
                __hip_bfloat16* dst = (l < 2) ? t0b : brsb[mb];
                k_gat<<<2048, 256, 0, stream>>>(xl8, xrb, at, bb, ioff, icsr, dst);
                lin = t0b;
            }
        }
        const float* resin = (st == 0) ? xn : img;
        if (st == 2) {
            k_ccfin<<<N_NODES / 128, 256, 0, stream>>>(b0b, b1b, b2b,
                ccpk + 2 * 12288, ccb + 128, resin, outp);
        } else {
            k_cc2<<<N_NODES / 128, 256, 0, stream>>>(b0b, b1b, b2b,
                ccpk + st * 12288, ccb + st * 64, resin, img, xb);
            for (int bk = 0; bk < 4; ++bk) {
                int cv = (st * 4 + bk) * 2;
                k_conv<0><<<512, 256, 0, stream>>>(xb, wpkc + (size_t)cv * 36864,
                    rbb + cv * 64, rba + st * 4 + bk, nullptr, cvb);
                k_conv<1><<<512, 256, 0, stream>>>(cvb, wpkc + (size_t)(cv + 1) * 36864,
                    rbb + (cv + 1) * 64, nullptr, img, xb);
            }
        }
    }
}

// Round 10
// 1294.651 us; speedup vs baseline: 1.4397x; 1.0095x over previous
//
#include <hip/hip_runtime.h>
#include <hip/hip_bf16.h>
#include <math.h>

#define N_NODES 65536
#define HW      65536
#define NE      524288
#define NC      (N_NODES * 64)

typedef __bf16 bf16x8 __attribute__((ext_vector_type(8)));
typedef float  f32x4  __attribute__((ext_vector_type(4)));
typedef float  f32x2  __attribute__((ext_vector_type(2)));
typedef int    i32x4  __attribute__((ext_vector_type(4)));
typedef unsigned int uint2v __attribute__((ext_vector_type(2)));

static __device__ __forceinline__ f32x4 mfma16(bf16x8 a, bf16x8 b, f32x4 c) {
    return __builtin_amdgcn_mfma_f32_16x16x32_bf16(a, b, c, 0, 0, 0);
}

static __device__ __forceinline__ unsigned short f2bs(float f) {
    return __builtin_bit_cast(unsigned short, __float2bfloat16(f));
}

static __device__ __forceinline__ void unpack4(uint2v xw, f32x4& xj) {
    xj[0] = __builtin_bit_cast(float, xw[0] << 16);
    xj[1] = __builtin_bit_cast(float, xw[0] & 0xffff0000u);
    xj[2] = __builtin_bit_cast(float, xw[1] << 16);
    xj[3] = __builtin_bit_cast(float, xw[1] & 0xffff0000u);
}

static __device__ __forceinline__ void unpack_fp8(unsigned int w, f32x4& xj) {
    f32x2 lo = __builtin_amdgcn_cvt_pk_f32_fp8((int)w, false);
    f32x2 hi = __builtin_amdgcn_cvt_pk_f32_fp8((int)w, true);
    xj[0] = lo[0]; xj[1] = lo[1]; xj[2] = hi[0]; xj[3] = hi[1];
}

// ---------------- CSR build ----------------
__global__ void k_hist(const int* __restrict__ dstA, int* __restrict__ cnt) {
    int e = blockIdx.x * 256 + threadIdx.x;
    if (e < NE) atomicAdd(&cnt[dstA[e]], 1);
}

__global__ void k_scan(const int* __restrict__ cnt, int* __restrict__ off) {
    __shared__ int sums[1024];
    int t = threadIdx.x;
    int base = t * 64;
    int s = 0;
    for (int i = 0; i < 64; ++i) s += cnt[base + i];
    sums[t] = s;
    __syncthreads();
    for (int d = 1; d < 1024; d <<= 1) {
        int v = (t >= d) ? sums[t - d] : 0;
        __syncthreads();
        sums[t] += v;
        __syncthreads();
    }
    int run = sums[t] - s;  // exclusive prefix
    for (int i = 0; i < 64; ++i) { off[base + i] = run; run += cnt[base + i]; }
    if (t == 1023) off[N_NODES] = run;
}

__global__ void k_fill(const int* __restrict__ srcA, const int* __restrict__ dstA,
                       int* __restrict__ cur, int* __restrict__ csr) {
    int e = blockIdx.x * 256 + threadIdx.x;
    if (e < NE) {
        int p = atomicAdd(&cur[dstA[e]], 1);
        csr[p] = srcA[e];
    }
}

// ---------------- weight packing (MFMA fragment order) ----------------
// conv: rb_w [16][co][ci][3][3] -> [cv][tap][nt][kk][lane][8] bf16
__global__ void k_cvpack(const float* __restrict__ w, __hip_bfloat16* __restrict__ d) {
    int idx = blockIdx.x * 256 + threadIdx.x;
    if (idx >= 589824) return;
    int j = idx & 7, lane = (idx >> 3) & 63, r = idx >> 9;
    int kk = r & 1; r >>= 1;
    int nt = r & 3; r >>= 2;
    int tap = r % 9, cv = r / 9;
    int co = nt * 16 + (lane & 15);
    int ci = kk * 32 + (lane >> 4) * 8 + j;
    d[idx] = __float2bfloat16(w[((cv * 64 + co) * 64 + ci) * 9 + tap]);
}

// gat mm: gWl/gWr [27][ci][co] -> [lay][side][nt][kk][lane][8] bf16
__global__ void k_mmpack(const float* __restrict__ Wl, const float* __restrict__ Wr,
                         __hip_bfloat16* __restrict__ d) {
    int idx = blockIdx.x * 256 + threadIdx.x;
    if (idx >= 221184) return;
    int j = idx & 7, lane = (idx >> 3) & 63, r = idx >> 9;
    int kk = r & 1; r >>= 1;
    int nt = r & 3; r >>= 2;
    int side = r & 1, lay = r >> 1;
    int co = nt * 16 + (lane & 15);
    int ci = kk * 32 + (lane >> 4) * 8 + j;
    const float* W = side ? Wr : Wl;
    d[idx] = __float2bfloat16(W[lay * 4096 + ci * 64 + co]);
}

// cc_w [3][o=64][k=192] -> [st][br][nt][kk][lane][8] bf16
__global__ void k_ccpack(const float* __restrict__ w, __hip_bfloat16* __restrict__ d) {
    int idx = blockIdx.x * 256 + threadIdx.x;
    if (idx >= 36864) return;
    int j = idx & 7;
    int u = idx >> 3;
    int lane = u & 63;
    int f = (u >> 6) & 7;
    int sb = u >> 9;
    int kk = f & 1, nt = f >> 1;
    int br = sb % 3, st = sb / 3;
    int k = br * 64 + kk * 32 + (lane >> 4) * 8 + j;
    int co = nt * 16 + (lane & 15);
    d[idx] = __float2bfloat16(w[st * 12288 + co * 192 + k]);
}

// ---------------- initial NCHW -> [N,64] fp32 + bf16 ----------------
__global__ void k_init(const float* __restrict__ img, float* __restrict__ xn,
                       __hip_bfloat16* __restrict__ xb) {
    __shared__ float tile[64][65];
    int nb = blockIdx.x * 64;
    for (int idx = threadIdx.x; idx < 4096; idx += 256) {
        int c = idx >> 6, n = idx & 63;
        tile[c][n] = img[c * HW + nb + n];
    }
    __syncthreads();
    for (int idx = threadIdx.x; idx < 4096; idx += 256) {
        int n = idx >> 6, c = idx & 63;
        float v = tile[c][n];
        xn[(nb + n) * 64 + c] = v;
        xb[(nb + n) * 64 + c] = __float2bfloat16(v);
    }
}

// ---------------- MFMA dual matmul: XL8 = fp8(X@Wl), XRb = bf16(X@Wr) ----------------
// side-0 result is bounced through LDS so 8 consecutive channels land in one
// thread for fp8 packing (gather-side layout [node][ch] byte-contiguous).
__global__ __launch_bounds__(256) void k_mm(const __hip_bfloat16* __restrict__ Xb,
        const __hip_bfloat16* __restrict__ pw, unsigned char* __restrict__ XL8,
        __hip_bfloat16* __restrict__ XRb) {
    __shared__ char smem[17408];
    i32x4* la = (i32x4*)smem;
    int t = threadIdx.x, lane = t & 63, wid = t >> 6;
    int n0 = blockIdx.x * 128;
    const i32x4* Xg = (const i32x4*)Xb + n0 * 8;
    for (int idx = t; idx < 1024; idx += 256) {
        int r = idx >> 3, c = idx & 7;
        la[r * 8 + (c ^ (r & 7))] = Xg[idx];
    }
    int side = wid & 1, rh = wid >> 1;
    const i32x4* wpt = (const i32x4*)pw + side * 512 + lane;
    f32x4 acc[4][4];
#pragma unroll
    for (int mi = 0; mi < 4; ++mi)
#pragma unroll
        for (int nt = 0; nt < 4; ++nt) acc[mi][nt] = (f32x4)0.0f;
    bf16x8 b[4][2];
#pragma unroll
    for (int nt = 0; nt < 4; ++nt)
#pragma unroll
        for (int kk = 0; kk < 2; ++kk)
            b[nt][kk] = __builtin_bit_cast(bf16x8, wpt[(nt * 2 + kk) * 64]);
    __syncthreads();
#pragma unroll
    for (int mi = 0; mi < 4; ++mi) {
        int row = rh * 64 + mi * 16 + (lane & 15);
#pragma unroll
        for (int kk = 0; kk < 2; ++kk) {
            bf16x8 a = __builtin_bit_cast(bf16x8,
                la[row * 8 + (((kk << 2) | (lane >> 4)) ^ (row & 7))]);
#pragma unroll
            for (int nt = 0; nt < 4; ++nt)
                acc[mi][nt] = mfma16(a, b[nt][kk], acc[mi][nt]);
        }
    }
    __syncthreads();                      // la consumed; repurpose as bf16 stage
    unsigned short* ls = (unsigned short*)smem;
    if (side == 0) {
#pragma unroll
        for (int mi = 0; mi < 4; ++mi)
#pragma unroll
            for (int nt = 0; nt < 4; ++nt) {
                int co = nt * 16 + (lane & 15);
#pragma unroll
                for (int r = 0; r < 4; ++r) {
                    int row = rh * 64 + mi * 16 + (lane >> 4) * 4 + r;
                    ls[row * 68 + co] = f2bs(acc[mi][nt][r]);
                }
            }
    } else {
#pragma unroll
        for (int mi = 0; mi < 4; ++mi)
#pragma unroll
            for (int nt = 0; nt < 4; ++nt) {
                int co = nt * 16 + (lane & 15);
#pragma unroll
                for (int r = 0; r < 4; ++r) {
                    int node = n0 + rh * 64 + mi * 16 + (lane >> 4) * 4 + r;
                    XRb[node * 64 + co] = __float2bfloat16(acc[mi][nt][r]);
                }
            }
    }
    __syncthreads();
    for (int u = t; u < 1024; u += 256) {     // 128 nodes x 8 channel-octs
        int node = u >> 3, oct = u & 7;
        const unsigned short* p = ls + node * 68 + oct * 8;
        uint2v w0 = *(const uint2v*)p;
        uint2v w1 = *(const uint2v*)(p + 4);
        float f0 = __builtin_bit_cast(float, w0[0] << 16);
        float f1 = __builtin_bit_cast(float, w0[0] & 0xffff0000u);
        float f2 = __builtin_bit_cast(float, w0[1] << 16);
        float f3 = __builtin_bit_cast(float, w0[1] & 0xffff0000u);
        float f4 = __builtin_bit_cast(float, w1[0] << 16);
        float f5 = __builtin_bit_cast(float, w1[0] & 0xffff0000u);
        float f6 = __builtin_bit_cast(float, w1[1] << 16);
        float f7 = __builtin_bit_cast(float, w1[1] & 0xffff0000u);
        int v0 = 0, v1 = 0;
        v0 = __builtin_amdgcn_cvt_pk_fp8_f32(f0, f1, v0, false);
        v0 = __builtin_amdgcn_cvt_pk_fp8_f32(f2, f3, v0, true);
        v1 = __builtin_amdgcn_cvt_pk_fp8_f32(f4, f5, v1, false);
        v1 = __builtin_amdgcn_cvt_pk_fp8_f32(f6, f7, v1, true);
        uint2v o;
        o[0] = (unsigned)v0;
        o[1] = (unsigned)v1;
        *(uint2v*)(XL8 + (size_t)(n0 + node) * 64 + oct * 8) = o;
    }
}

// ---------------- GAT edge phase (fp8 gather) ----------------
// 16-lane group owns one node (4 ch/lane). Per-head softmax = quad reduce only.
__global__ __launch_bounds__(256) void k_gat(const unsigned char* __restrict__ XL8,
        const __hip_bfloat16* __restrict__ XRb, const float* __restrict__ att64,
        const float* __restrict__ bias, const int* __restrict__ off,
        const int* __restrict__ csr, __hip_bfloat16* __restrict__ outb) {
    __shared__ int csr_c[320];
    int tid = threadIdx.x;
    int lane = tid & 63;
    int g = (lane >> 4) & 3;
    int c4 = (lane & 15) << 2;
    int nblk = blockIdx.x * 32;
    int cbase = off[nblk];
    int ccnt = min(off[nblk + 32] - cbase, 320);
    for (int idx = tid; idx < ccnt; idx += 256) csr_c[idx] = csr[cbase + idx];
    __syncthreads();
    const float LOG2E = 1.44269504089f;
    f32x4 a4 = *(const f32x4*)(att64 + c4);
#pragma unroll
    for (int j = 0; j < 4; ++j) a4[j] *= LOG2E;
    f32x4 b4 = *(const f32x4*)(bias + c4);
    int base = nblk + ((tid >> 6) << 3) + g * 2;   // 2 consecutive nodes per group
#pragma unroll
    for (int nn = 0; nn < 2; ++nn) {
        int n = base + nn;
        int e0 = off[n], e1 = off[n + 1];
        uint2v xw = *(const uint2v*)(XRb + n * 64 + c4);
        f32x4 xi;
        unpack4(xw, xi);
        float s = 0.f;
        f32x4 acc = (f32x4)0.0f;
        int rounds = (e1 - e0 + 1) >> 1;
        int e = e0;
        for (int i = 0; i < rounds; ++i, e += 2) {
            bool aB = (e + 1) < e1;
            int eB = aB ? e + 1 : e;
            int rA = e - cbase, rB = eB - cbase;
            int sA = (rA < ccnt) ? csr_c[rA] : csr[e];
            int sB = (rB < ccnt) ? csr_c[rB] : csr[eB];
            unsigned int wA = *(const unsigned int*)(XL8 + (size_t)sA * 64 + c4);
            unsigned int wB = *(const unsigned int*)(XL8 + (size_t)sB * 64 + c4);
            f32x4 xjA, xjB;
            unpack_fp8(wA, xjA);
            unpack_fp8(wB, xjB);
            float pA = 0.f, pB = 0.f;
#pragma unroll
            for (int j = 0; j < 4; ++j) {
                float vA = xi[j] + xjA[j];
                vA = fmaxf(vA, 0.2f * vA);       // leaky_relu(0.2)
                pA = fmaf(vA, a4[j], pA);
                float vB = xi[j] + xjB[j];
                vB = fmaxf(vB, 0.2f * vB);
                pB = fmaf(vB, a4[j], pB);
            }
            pA += __shfl_xor(pA, 1);
            pA += __shfl_xor(pA, 2);             // per-head logit (quad reduce)
            pB += __shfl_xor(pB, 1);
            pB += __shfl_xor(pB, 2);
            float exA = exp2f(fmaxf(pA, -100.f));    // shift-invariant softmax
            float exB = exp2f(fmaxf(pB, -100.f));
            exB = aB ? exB : 0.f;
            s += exA + exB;
#pragma unroll
            for (int j = 0; j < 4; ++j)
                acc[j] = fmaf(exA, xjA[j], fmaf(exB, xjB[j], acc[j]));
        }
        float inv = __builtin_amdgcn_rcpf(s + 1e-16f);
        float v0 = fmaf(acc[0], inv, b4[0]);
        float v1 = fmaf(acc[1], inv, b4[1]);
        float v2 = fmaf(acc[2], inv, b4[2]);
        float v3 = fmaf(acc[3], inv, b4[3]);
        v0 = v0 > 0.f ? v0 : __expf(v0) - 1.f;   // ELU
        v1 = v1 > 0.f ? v1 : __expf(v1) - 1.f;
        v2 = v2 > 0.f ? v2 : __expf(v2) - 1.f;
        v3 = v3 > 0.f ? v3 : __expf(v3) - 1.f;
        uint2v o;
        o[0] = (unsigned)f2bs(v0) | ((unsigned)f2bs(v1) << 16);
        o[1] = (unsigned)f2bs(v2) | ((unsigned)f2bs(v3) << 16);
        *(uint2v*)(outb + n * 64 + c4) = o;
    }
}

// ---------------- 1x1 conv (MFMA): out = cat(b0,b1,b2)@W + bias + res ----------------
__global__ __launch_bounds__(256) void k_cc2(const __hip_bfloat16* __restrict__ b0,
        const __hip_bfloat16* __restrict__ b1, const __hip_bfloat16* __restrict__ b2,
        const __hip_bfloat16* __restrict__ pw, const float* __restrict__ bias,
        const float* __restrict__ resin, float* __restrict__ imgout,
        __hip_bfloat16* __restrict__ outb) {
    __shared__ i32x4 la[128 * 8];
    int t = threadIdx.x, lane = t & 63, wid = t >> 6;
    int n0 = blockIdx.x * 128;
    const __hip_bfloat16* brs[3] = {b0, b1, b2};
    const i32x4* wp4 = (const i32x4*)pw;
    f32x4 acc[2][4];
#pragma unroll
    for (int mi = 0; mi < 2; ++mi)
#pragma unroll
        for (int nt = 0; nt < 4; ++nt) acc[mi][nt] = (f32x4)0.0f;
#pragma unroll
    for (int br = 0; br < 3; ++br) {
        __syncthreads();
        const i32x4* Bg = (const i32x4*)brs[br] + n0 * 8;
        for (int idx = t; idx < 1024; idx += 256) {
            int r = idx >> 3, c = idx & 7;
            la[r * 8 + (c ^ (r & 7))] = Bg[idx];
        }
        __syncthreads();
        bf16x8 bf[4][2];
#pragma unroll
        for (int nt = 0; nt < 4; ++nt)
#pragma unroll
            for (int kk = 0; kk < 2; ++kk)
                bf[nt][kk] = __builtin_bit_cast(bf16x8,
                    wp4[(br * 8 + nt * 2 + kk) * 64 + lane]);
#pragma unroll
        for (int mi = 0; mi < 2; ++mi) {
            int row = wid * 32 + mi * 16 + (lane & 15);
#pragma unroll
            for (int kk = 0; kk < 2; ++kk) {
                bf16x8 a = __builtin_bit_cast(bf16x8,
                    la[row * 8 + (((kk << 2) | (lane >> 4)) ^ (row & 7))]);
#pragma unroll
                for (int nt = 0; nt < 4; ++nt)
                    acc[mi][nt] = mfma16(a, bf[nt][kk], acc[mi][nt]);
            }
        }
    }
#pragma unroll
    for (int mi = 0; mi < 2; ++mi)
#pragma unroll
        for (int nt = 0; nt < 4; ++nt) {
            int co = nt * 16 + (lane & 15);
            float bv = bias[co];
#pragma unroll
            for (int r = 0; r < 4; ++r) {
                int node = n0 + wid * 32 + mi * 16 + (lane >> 4) * 4 + r;
                float v = acc[mi][nt][r] + bv + resin[node * 64 + co];
                imgout[node * 64 + co] = v;
                outb[node * 64 + co] = __float2bfloat16(v);
            }
        }
}

// final stage: same GEMM, output NCHW fp32 via LDS transpose
__global__ __launch_bounds__(256) void k_ccfin(const __hip_bfloat16* __restrict__ b0,
        const __hip_bfloat16* __restrict__ b1, const __hip_bfloat16* __restrict__ b2,
        const __hip_bfloat16* __restrict__ pw, const float* __restrict__ bias,
        const float* __restrict__ resin, float* __restrict__ outp) {
    __shared__ i32x4 la[128 * 8];
    __shared__ float tt[64][132];
    int t = threadIdx.x, lane = t & 63, wid = t >> 6;
    int n0 = blockIdx.x * 128;
    const __hip_bfloat16* brs[3] = {b0, b1, b2};
    const i32x4* wp4 = (const i32x4*)pw;
    f32x4 acc[2][4];
#pragma unroll
    for (int mi = 0; mi < 2; ++mi)
#pragma unroll
        for (int nt = 0; nt < 4; ++nt) acc[mi][nt] = (f32x4)0.0f;
#pragma unroll
    for (int br = 0; br < 3; ++br) {
        __syncthreads();
        const i32x4* Bg = (const i32x4*)brs[br] + n0 * 8;
        for (int idx = t; idx < 1024; idx += 256) {
            int r = idx >> 3, c = idx & 7;
            la[r * 8 + (c ^ (r & 7))] = Bg[idx];
        }
        __syncthreads();
        bf16x8 bf[4][2];
#pragma unroll
        for (int nt = 0; nt < 4; ++nt)
#pragma unroll
            for (int kk = 0; kk < 2; ++kk)
                bf[nt][kk] = __builtin_bit_cast(bf16x8,
                    wp4[(br * 8 + nt * 2 + kk) * 64 + lane]);
#pragma unroll
        for (int mi = 0; mi < 2; ++mi) {
            int row = wid * 32 + mi * 16 + (lane & 15);
#pragma unroll
            for (int kk = 0; kk < 2; ++kk) {
                bf16x8 a = __builtin_bit_cast(bf16x8,
                    la[row * 8 + (((kk << 2) | (lane >> 4)) ^ (row & 7))]);
#pragma unroll
                for (int nt = 0; nt < 4; ++nt)
                    acc[mi][nt] = mfma16(a, bf[nt][kk], acc[mi][nt]);
            }
        }
    }
#pragma unroll
    for (int mi = 0; mi < 2; ++mi)
#pragma unroll
        for (int nt = 0; nt < 4; ++nt) {
            int co = nt * 16 + (lane & 15);
            float bv = bias[co];
#pragma unroll
            for (int r = 0; r < 4; ++r) {
                int nl = wid * 32 + mi * 16 + (lane >> 4) * 4 + r;
                tt[co][nl] = acc[mi][nt][r] + bv + resin[(n0 + nl) * 64 + co];
            }
        }
    __syncthreads();
    for (int u = t; u < 2048; u += 256) {
        int row = u >> 5;
        int col = (u & 31) * 4;
        f32x4 v = *(const f32x4*)&tt[row][col];
        *(f32x4*)(outp + row * HW + n0 + col) = v;
    }
}

// ---------------- 3x3 conv 64->64, channels-last, MFMA, dy double-buffer ----------------
template <int MODE>
__global__ __launch_bounds__(256) void k_conv(const __hip_bfloat16* __restrict__ inb,
        const __hip_bfloat16* __restrict__ wp, const float* __restrict__ bias,
        const float* __restrict__ pa, float* __restrict__ img,
        __hip_bfloat16* __restrict__ outb) {
    __shared__ i32x4 la[2][130 * 8];
    int t = threadIdx.x, lane = t & 63, wid = t >> 6;
    int y = blockIdx.x >> 1, x0 = (blockIdx.x & 1) << 7;
    f32x4 acc[2][4];
#pragma unroll
    for (int mi = 0; mi < 2; ++mi)
#pragma unroll
        for (int nt = 0; nt < 4; ++nt) acc[mi][nt] = (f32x4)0.0f;
    const i32x4* ing = (const i32x4*)inb;
    auto stage = [&](int dy, int buf) {
        int sy = y + dy - 1;
        bool rowok = (sy >= 0) && (sy < 256);
        for (int idx = t; idx < 1040; idx += 256) {
            int r = idx >> 3, c = idx & 7;
            int sx = x0 - 1 + r;
            i32x4 v = (i32x4)0;
            if (rowok && sx >= 0 && sx < 256) v = ing[(sy * 256 + sx) * 8 + c];
            la[buf][r * 8 + (c ^ (r & 7))] = v;
        }
    };
    stage(0, 0);
    __syncthreads();
#pragma unroll
    for (int dy = 0; dy < 3; ++dy) {
        if (dy < 2) stage(dy + 1, (dy + 1) & 1);   // prefetch next row while computing
        const i32x4* lb = la[dy & 1];
#pragma unroll
        for (int dx = 0; dx < 3; ++dx) {
            const i32x4* wpt = (const i32x4*)wp + (dy * 3 + dx) * 512 + lane;
            bf16x8 b[4][2];
#pragma unroll
            for (int nt = 0; nt < 4; ++nt)
#pragma unroll
                for (int kk = 0; kk < 2; ++kk)
                    b[nt][kk] = __builtin_bit_cast(bf16x8, wpt[(nt * 2 + kk) * 64]);
#pragma unroll
            for (int mi = 0; mi < 2; ++mi) {
                int row = dx + wid * 32 + mi * 16 + (lane & 15);
#pragma unroll
                for (int kk = 0; kk < 2; ++kk) {
                    bf16x8 a = __builtin_bit_cast(bf16x8,
                        lb[row * 8 + (((kk << 2) | (lane >> 4)) ^ (row & 7))]);
#pragma unroll
                    for (int nt = 0; nt < 4; ++nt)
                        acc[mi][nt] = mfma16(a, b[nt][kk], acc[mi][nt]);
                }
            }
        }
        __syncthreads();
    }
    int pbase = y * 256 + x0 + wid * 32 + (lane >> 4) * 4;
    float aprelu = (MODE == 0) ? pa[0] : 0.f;
#pragma unroll
    for (int mi = 0; mi < 2; ++mi)
#pragma unroll
        for (int nt = 0; nt < 4; ++nt) {
            int co = nt * 16 + (lane & 15);
            float bv = bias[co];
#pragma unroll
            for (int r = 0; r < 4; ++r) {
                int pix = pbase + mi * 16 + r;
                float v = acc[mi][nt][r] + bv;
                if (MODE == 0) {
                    v = v >= 0.f ? v : aprelu * v;
                    outb[pix * 64 + co] = __float2bfloat16(v);
                } else {
                    v += img[pix * 64 + co];
                    img[pix * 64 + co] = v;
                    outb[pix * 64 + co] = __float2bfloat16(v);
                }
            }
        }
}

// ---------------- host ----------------
extern "C" void kernel_launch(void* const* d_in, const int* in_sizes, int n_in,
                              void* d_out, int out_size, void* d_ws, size_t ws_size,
                              hipStream_t stream) {
    const float* x    = (const float*)d_in[0];
    const int*   ei   = (const int*)d_in[1];
    const float* gWl  = (const float*)d_in[2];   // [27][64][64]
    const float* gWr  = (const float*)d_in[3];
    const float* gatt = (const float*)d_in[4];   // [27][64]
    const float* gb   = (const float*)d_in[5];   // [27][64]
    const float* ccw  = (const float*)d_in[6];   // [3][64][192]
    const float* ccb  = (const float*)d_in[7];   // [3][64]
    const float* rbw  = (const float*)d_in[8];   // [16][64][64][3][3]
    const float* rbb  = (const float*)d_in[9];   // [16][64]
    const float* rba  = (const float*)d_in[10];  // [8]
    float* outp = (float*)d_out;

    float* wsf = (float*)d_ws;
    float* xn  = wsf;            // [N,64] fp32 stage-0 residual
    float* xrs = xn  + NC;       // slot reused as bf16 XRb
    float* img = xrs + NC;       // [N,64] fp32 running image
    __hip_bfloat16* xrb  = (__hip_bfloat16*)xrs;
    unsigned char*  xl8  = (unsigned char*)(img + NC);     // NC bytes fp8 XL
    __hip_bfloat16* xb   = (__hip_bfloat16*)(img + NC) + NC;
    __hip_bfloat16* t0b  = xb  + NC;
    __hip_bfloat16* cvb  = t0b + NC;
    __hip_bfloat16* b0b  = cvb + NC;
    __hip_bfloat16* b1b  = b0b + NC;
    __hip_bfloat16* b2b  = b1b + NC;
    __hip_bfloat16* wpkc = b2b + NC;        // 589824
    __hip_bfloat16* wpkm = wpkc + 589824;   // 221184
    __hip_bfloat16* ccpk = wpkm + 221184;   // 36864
    int* ioff = (int*)(ccpk + 36864);
    int* icnt = ioff + (N_NODES + 1);
    int* icur = icnt + N_NODES;
    int* icsr = icur + N_NODES;             // NE

    const int* srcA = ei;
    const int* dstA = ei + NE;

    hipMemsetAsync(icnt, 0, N_NODES * sizeof(int), stream);
    k_hist<<<NE / 256, 256, 0, stream>>>(dstA, icnt);
    k_scan<<<1, 1024, 0, stream>>>(icnt, ioff);
    hipMemcpyAsync(icur, ioff, N_NODES * sizeof(int), hipMemcpyDeviceToDevice, stream);
    k_fill<<<NE / 256, 256, 0, stream>>>(srcA, dstA, icur, icsr);
    k_cvpack<<<2304, 256, 0, stream>>>(rbw, wpkc);
    k_mmpack<<<864, 256, 0, stream>>>(gWl, gWr, wpkm);
    k_ccpack<<<144, 256, 0, stream>>>(ccw, ccpk);
    k_init<<<1024, 256, 0, stream>>>(x, xn, xb);

    __hip_bfloat16* brsb[3] = {b0b, b1b, b2b};
    for (int st = 0; st < 3; ++st) {
        for (int mb = 0; mb < 3; ++mb) {
            const __hip_bfloat16* lin = xb;
            for (int l = 0; l < 3; ++l) {
                int lay = (st * 3 + mb) * 3 + l;
                k_mm<<<N_NODES / 128, 256, 0, stream>>>(lin, wpkm + lay * 8192, xl8, xrb);
                const float* at = gatt + lay * 64;
                const float* bb = gb + lay * 64;
                __hip_bfloat16* dst = (l < 2) ? t0b : brsb[mb];
                k_gat<<<2048, 256, 0, stream>>>(xl8, xrb, at, bb, ioff, icsr, dst);
                lin = t0b;
            }
        }
        const float* resin = (st == 0) ? xn : img;
        if (st == 2) {
            k_ccfin<<<N_NODES / 128, 256, 0, stream>>>(b0b, b1b, b2b,
                ccpk + 2 * 12288, ccb + 128, resin, outp);
        } else {
            k_cc2<<<N_NODES / 128, 256, 0, stream>>>(b0b, b1b, b2b,
                ccpk + st * 12288, ccb + st * 64, resin, img, xb);
            for (int bk = 0; bk < 4; ++bk) {
                int cv = (st * 4 + bk) * 2;
                k_conv<0><<<512, 256, 0, stream>>>(xb, wpkc + (size_t)cv * 36864,
                    rbb + cv * 64, rba + st * 4 + bk, nullptr, cvb);
                k_conv<1><<<512, 256, 0, stream>>>(cvb, wpkc + (size_t)(cv + 1) * 36864,
                    rbb + (cv + 1) * 64, nullptr, img, xb);
            }
        }
    }
}